// Round 1
// baseline (644.295 us; speedup 1.0000x reference)
//
#include <hip/hip_runtime.h>
#include <math.h>

#define B_ 4
#define H_ 12
#define N_ 1025
#define D_ 64
#define HID_ 32
#define TBL_ 3969   // (2*32-1)^2
#define KT 64       // k-tile rows
#define QT 128      // q-rows per block (2 lanes per row, 256 threads)
#define NQT 9       // ceil(1025/128)

// ---------------- bias-table MLP: btT[h][i] = (gelu(rel @ w1 + b1) @ w2)[i][h]
__global__ void cpb_mlp(const float* __restrict__ rel, const float* __restrict__ w1,
                        const float* __restrict__ b1, const float* __restrict__ w2,
                        float* __restrict__ btT) {
    int i = blockIdx.x * 256 + threadIdx.x;
    if (i >= TBL_) return;
    float x0 = rel[2 * i + 0], x1 = rel[2 * i + 1];
    float acc[H_];
#pragma unroll
    for (int h = 0; h < H_; ++h) acc[h] = 0.f;
#pragma unroll
    for (int j = 0; j < HID_; ++j) {
        float t = fmaf(x0, w1[j], fmaf(x1, w1[HID_ + j], b1[j]));
        float g = 0.5f * t * (1.f + erff(t * 0.7071067811865475f));  // exact gelu
#pragma unroll
        for (int h = 0; h < H_; ++h) acc[h] = fmaf(g, w2[j * H_ + h], acc[h]);
    }
#pragma unroll
    for (int h = 0; h < H_; ++h) btT[h * TBL_ + i] = acc[h];
}

// ---------------- fused flash attention with contextual position bias
__global__ void flex_attn(const float* __restrict__ Q, const float* __restrict__ K,
                          const float* __restrict__ V, const float* __restrict__ MU,
                          const float* __restrict__ GAMMA, const float* __restrict__ btT,
                          float* __restrict__ OUT) {
    __shared__ float Ks[KT][D_];
    __shared__ float Vs[KT][D_];
    __shared__ float aks[KT];  // sg * mu_k[k]
    __shared__ int cks[KT];    // bias column code, -1 = no bias

    const int bh = blockIdx.x / NQT;
    const int qt = blockIdx.x % NQT;
    const int h = bh % H_;
    const int tid = threadIdx.x;
    const int r = qt * QT + (tid >> 1);  // q row
    const int half = tid & 1;            // which 32 dims of D
    const bool qv = r < N_;

    const size_t base = (size_t)bh * N_ * D_;
    const float sg = 1.f / (1.f + __expf(-GAMMA[h]));

    float qr[32];
    if (qv) {
        const float4* qp = (const float4*)(Q + base + (size_t)r * D_ + half * 32);
#pragma unroll
        for (int i = 0; i < 8; ++i) {
            float4 t = qp[i];
            qr[4 * i + 0] = t.x; qr[4 * i + 1] = t.y;
            qr[4 * i + 2] = t.z; qr[4 * i + 3] = t.w;
        }
    } else {
#pragma unroll
        for (int i = 0; i < 32; ++i) qr[i] = 0.f;
    }

    const bool qb = qv && (r >= 1);
    int cq = 0;
    float aq = 0.f;
    if (qb) {
        int pq = r - 1;
        cq = (pq >> 5) * 63 + (pq & 31);
        aq = sg * MU[(size_t)bh * 2 * N_ + r];  // mu_q
    }
    // bias value = btT[h][cq - ck + 1984]  (verified vs meshgrid construction)
    const float* bth = btT + h * TBL_ + (cq + 1984);

    float m = -1e30f, l = 0.f;
    float o[32];
#pragma unroll
    for (int i = 0; i < 32; ++i) o[i] = 0.f;

    for (int kt0 = 0; kt0 < N_; kt0 += KT) {
        __syncthreads();
        // stage K,V tile: 4096 floats each, 256 threads x 4 float4-iters
#pragma unroll
        for (int it = 0; it < (KT * D_) / (256 * 4); ++it) {
            int e4 = it * 256 + tid;
            int kj = e4 >> 4;
            int kd = (e4 & 15) << 2;
            int kg = kt0 + kj;
            float4 kk = make_float4(0, 0, 0, 0), vv = make_float4(0, 0, 0, 0);
            if (kg < N_) {
                kk = *(const float4*)(K + base + (size_t)kg * D_ + kd);
                vv = *(const float4*)(V + base + (size_t)kg * D_ + kd);
            }
            *(float4*)&Ks[kj][kd] = kk;
            *(float4*)&Vs[kj][kd] = vv;
        }
        if (tid < KT) {
            int kg = kt0 + tid;
            float a = 0.f;
            int c = -1;
            if (kg >= 1 && kg < N_) {
                int pk = kg - 1;
                c = (pk >> 5) * 63 + (pk & 31);
                a = sg * MU[((size_t)bh * 2 + 1) * N_ + kg];  // mu_k
            }
            aks[tid] = a;
            cks[tid] = c;
        }
        __syncthreads();

        for (int j0 = 0; j0 < KT; j0 += 16) {
            float s[16];
#pragma unroll
            for (int jj = 0; jj < 16; ++jj) {
                int j = j0 + jj;
                const float4* kr = (const float4*)&Ks[j][half * 32];
                float a0 = 0, a1 = 0, a2 = 0, a3 = 0;
#pragma unroll
                for (int i4 = 0; i4 < 8; ++i4) {
                    float4 kk = kr[i4];
                    a0 = fmaf(qr[4 * i4 + 0], kk.x, a0);
                    a1 = fmaf(qr[4 * i4 + 1], kk.y, a1);
                    a2 = fmaf(qr[4 * i4 + 2], kk.z, a2);
                    a3 = fmaf(qr[4 * i4 + 3], kk.w, a3);
                }
                float acc = (a0 + a1) + (a2 + a3);
                acc += __shfl_xor(acc, 1);  // combine the two D-halves
                acc *= 0.125f;              // 1/sqrt(64)
                int c = cks[j];
                if (qb && c >= 0) acc = fmaf(aq + aks[j], bth[-c], acc);
                if (kt0 + j >= N_) acc = -1e30f;
                s[jj] = acc;
            }
            float mt = s[0];
#pragma unroll
            for (int jj = 1; jj < 16; ++jj) mt = fmaxf(mt, s[jj]);
            if (mt > m) {
                float cc = __expf(m - mt);
                m = mt;
                l *= cc;
#pragma unroll
                for (int i = 0; i < 32; ++i) o[i] *= cc;
            }
#pragma unroll
            for (int jj = 0; jj < 16; ++jj) {
                float p = __expf(s[jj] - m);
                l += p;
                const float4* vr = (const float4*)&Vs[j0 + jj][half * 32];
#pragma unroll
                for (int i4 = 0; i4 < 8; ++i4) {
                    float4 vv = vr[i4];
                    o[4 * i4 + 0] = fmaf(p, vv.x, o[4 * i4 + 0]);
                    o[4 * i4 + 1] = fmaf(p, vv.y, o[4 * i4 + 1]);
                    o[4 * i4 + 2] = fmaf(p, vv.z, o[4 * i4 + 2]);
                    o[4 * i4 + 3] = fmaf(p, vv.w, o[4 * i4 + 3]);
                }
            }
        }
    }

    if (qv) {
        float inv = 1.f / l;
        float4* op = (float4*)(OUT + base + (size_t)r * D_ + half * 32);
#pragma unroll
        for (int i4 = 0; i4 < 8; ++i4) {
            op[i4] = make_float4(o[4 * i4 + 0] * inv, o[4 * i4 + 1] * inv,
                                 o[4 * i4 + 2] * inv, o[4 * i4 + 3] * inv);
        }
    }
}

extern "C" void kernel_launch(void* const* d_in, const int* in_sizes, int n_in,
                              void* d_out, int out_size, void* d_ws, size_t ws_size,
                              hipStream_t stream) {
    const float* q = (const float*)d_in[0];
    const float* k = (const float*)d_in[1];
    const float* v = (const float*)d_in[2];
    const float* mu = (const float*)d_in[3];
    const float* w1 = (const float*)d_in[4];
    const float* b1 = (const float*)d_in[5];
    const float* w2 = (const float*)d_in[6];
    const float* gamma = (const float*)d_in[7];
    const float* rel = (const float*)d_in[8];
    // d_in[9] = idx_table: reconstructed analytically, never read.

    float* btT = (float*)d_ws;  // H_ * TBL_ floats = 190 KB

    cpb_mlp<<<(TBL_ + 255) / 256, 256, 0, stream>>>(rel, w1, b1, w2, btT);
    flex_attn<<<B_ * H_ * NQT, 256, 0, stream>>>(q, k, v, mu, gamma, btT, (float*)d_out);
}

// Round 2
// 103.877 us; speedup vs baseline: 6.2025x; 6.2025x over previous
//
#include <hip/hip_runtime.h>
#include <math.h>

#define B_ 4
#define H_ 12
#define N_ 1025
#define D_ 64
#define HID_ 32
#define TBL_ 3969   // (2*32-1)^2
#define KT 64       // k-tile rows
#define NQT 17      // ceil(1025/64)
#define NBLK (B_ * H_ * NQT)  // 816, divisible by 8

typedef _Float16 half8 __attribute__((ext_vector_type(8)));
typedef _Float16 half4v __attribute__((ext_vector_type(4)));
typedef float f32x4 __attribute__((ext_vector_type(4)));

// ---------------- bias-table MLP: btT[h][i] = (gelu(rel @ w1 + b1) @ w2)[i][h]
__global__ void cpb_mlp(const float* __restrict__ rel, const float* __restrict__ w1,
                        const float* __restrict__ b1, const float* __restrict__ w2,
                        float* __restrict__ btT) {
    int i = blockIdx.x * 256 + threadIdx.x;
    if (i >= TBL_) return;
    float x0 = rel[2 * i + 0], x1 = rel[2 * i + 1];
    float acc[H_];
#pragma unroll
    for (int h = 0; h < H_; ++h) acc[h] = 0.f;
#pragma unroll
    for (int j = 0; j < HID_; ++j) {
        float t = fmaf(x0, w1[j], fmaf(x1, w1[HID_ + j], b1[j]));
        float g = 0.5f * t * (1.f + erff(t * 0.7071067811865475f));  // exact gelu
#pragma unroll
        for (int h = 0; h < H_; ++h) acc[h] = fmaf(g, w2[j * H_ + h], acc[h]);
    }
#pragma unroll
    for (int h = 0; h < H_; ++h) btT[h * TBL_ + i] = acc[h];
}

// ---------------- fused flash attention, f16 MFMA
__global__ void flex_attn(const float* __restrict__ Q, const float* __restrict__ K,
                          const float* __restrict__ V, const float* __restrict__ MU,
                          const float* __restrict__ GAMMA, const float* __restrict__ btT,
                          float* __restrict__ OUT) {
    // K tile, row-major [k][d] f16, XOR-swizzled: hw idx = k*64 + (d ^ ((k&7)<<3))
    __shared__ __align__(16) _Float16 Ks[KT * 64];
    // V tile transposed [d][k] f16, same swizzle: idx = d*64 + (k ^ ((d&7)<<3))
    __shared__ __align__(16) _Float16 Vt[64 * KT];
    // per-wave P tile [q 16][k 64 + 8 pad] f16
    __shared__ __align__(16) _Float16 Pl[4][16 * 72];
    __shared__ float2 akck[KT];  // (sg*mu_k, bits(ck))

    const int bid = blockIdx.x;
    const int swz = (bid & 7) * (NBLK / 8) + (bid >> 3);  // XCD-contiguous
    const int bh = swz / NQT;
    const int qt = swz % NQT;
    const int h = bh % H_;
    const int tid = threadIdx.x;
    const int w = tid >> 6;
    const int lane = tid & 63;
    const int lq = lane & 15;  // q within wave tile / mfma col
    const int g = lane >> 4;   // 4-lane group

    const size_t base = (size_t)bh * (N_ * D_);
    const float sg = 1.f / (1.f + __expf(-GAMMA[h]));

    const int qrow = qt * 64 + w * 16 + lq;
    const bool qv = qrow < N_;

    // Q fragment (B-operand of swapped QK^T): lane holds Q[qrow][dh*32 + g*8 + f] * 0.125
    half8 qf[2];
#pragma unroll
    for (int dh = 0; dh < 2; ++dh) {
        float4 t0 = make_float4(0, 0, 0, 0), t1 = t0;
        if (qv) {
            const float* qp = Q + base + (size_t)qrow * D_ + dh * 32 + g * 8;
            t0 = ((const float4*)qp)[0];
            t1 = ((const float4*)qp)[1];
        }
        half8 q8;
        q8[0] = (_Float16)(t0.x * 0.125f); q8[1] = (_Float16)(t0.y * 0.125f);
        q8[2] = (_Float16)(t0.z * 0.125f); q8[3] = (_Float16)(t0.w * 0.125f);
        q8[4] = (_Float16)(t1.x * 0.125f); q8[5] = (_Float16)(t1.y * 0.125f);
        q8[6] = (_Float16)(t1.z * 0.125f); q8[7] = (_Float16)(t1.w * 0.125f);
        qf[dh] = q8;
    }

    const bool qb = qv && (qrow >= 1);
    int cq = 0;
    float aq = 0.f;
    if (qb) {
        int pq = qrow - 1;
        cq = (pq >> 5) * 63 + (pq & 31);
        aq = sg * MU[(size_t)bh * 2 * N_ + qrow];  // sg*mu_q
    }
    const float* bthp = btT + h * TBL_ + cq + 1984;  // bias = bthp[-ck]

    f32x4 o[4];
    const f32x4 zz = {0.f, 0.f, 0.f, 0.f};
#pragma unroll
    for (int dg = 0; dg < 4; ++dg) o[dg] = zz;
    float m = -1e30f, lsum = 0.f;

    for (int kt0 = 0; kt0 < N_; kt0 += KT) {
        __syncthreads();
        // ---- stage K (f16, swizzled) and V^T (f16, swizzled)
        {
            const int k = tid >> 2;
            const int dc = (tid & 3) << 4;
            const int kg = kt0 + k;
            float4 k0 = make_float4(0, 0, 0, 0), k1 = k0, k2 = k0, k3 = k0;
            float4 v0 = k0, v1 = k0, v2 = k0, v3 = k0;
            if (kg < N_) {
                const float* kp = K + base + (size_t)kg * D_ + dc;
                const float* vp = V + base + (size_t)kg * D_ + dc;
                k0 = ((const float4*)kp)[0]; k1 = ((const float4*)kp)[1];
                k2 = ((const float4*)kp)[2]; k3 = ((const float4*)kp)[3];
                v0 = ((const float4*)vp)[0]; v1 = ((const float4*)vp)[1];
                v2 = ((const float4*)vp)[2]; v3 = ((const float4*)vp)[3];
            }
            const int swzk = (k & 7) << 3;
            half8 ka, kb;
            ka[0] = (_Float16)k0.x; ka[1] = (_Float16)k0.y; ka[2] = (_Float16)k0.z; ka[3] = (_Float16)k0.w;
            ka[4] = (_Float16)k1.x; ka[5] = (_Float16)k1.y; ka[6] = (_Float16)k1.z; ka[7] = (_Float16)k1.w;
            kb[0] = (_Float16)k2.x; kb[1] = (_Float16)k2.y; kb[2] = (_Float16)k2.z; kb[3] = (_Float16)k2.w;
            kb[4] = (_Float16)k3.x; kb[5] = (_Float16)k3.y; kb[6] = (_Float16)k3.z; kb[7] = (_Float16)k3.w;
            *(half8*)&Ks[k * 64 + (dc ^ swzk)] = ka;
            *(half8*)&Ks[k * 64 + ((dc + 8) ^ swzk)] = kb;
            // transpose-scatter V: (i&7)-dependent swizzle is compile-time per unrolled i
#define VSC(vec, i0)                                                                  \
    Vt[(dc + i0 + 0) * 64 + (k ^ (((i0 + 0) & 7) << 3))] = (_Float16)vec.x;           \
    Vt[(dc + i0 + 1) * 64 + (k ^ (((i0 + 1) & 7) << 3))] = (_Float16)vec.y;           \
    Vt[(dc + i0 + 2) * 64 + (k ^ (((i0 + 2) & 7) << 3))] = (_Float16)vec.z;           \
    Vt[(dc + i0 + 3) * 64 + (k ^ (((i0 + 3) & 7) << 3))] = (_Float16)vec.w;
            VSC(v0, 0) VSC(v1, 4) VSC(v2, 8) VSC(v3, 12)
#undef VSC
        }
        if (tid < KT) {
            int kg2 = kt0 + tid;
            float a = 0.f;
            int c = -1;
            if (kg2 >= 1 && kg2 < N_) {
                int pk = kg2 - 1;
                c = (pk >> 5) * 63 + (pk & 31);
                a = sg * MU[((size_t)bh * 2 + 1) * N_ + kg2];  // sg*mu_k
            }
            akck[tid] = make_float2(a, __int_as_float(c));
        }
        __syncthreads();

        // ---- QK^T (swapped): C[k][q], A = K rows, B = Q^T
        f32x4 sa[4];
        const int arow_sw = (lq & 7) << 3;  // (k&7)<<3 with k = kg*16+lq
#pragma unroll
        for (int kg = 0; kg < 4; ++kg) {
            const int krow = kg * 16 + lq;
            half8 a0 = *(half8*)&Ks[krow * 64 + ((g * 8) ^ arow_sw)];
            half8 a1 = *(half8*)&Ks[krow * 64 + ((g * 8 + 32) ^ arow_sw)];
            f32x4 z = zz;
            z = __builtin_amdgcn_mfma_f32_16x16x32_f16(a0, qf[0], z, 0, 0, 0);
            z = __builtin_amdgcn_mfma_f32_16x16x32_f16(a1, qf[1], z, 0, 0, 0);
            sa[kg] = z;
        }

        // ---- bias + mask + online softmax (lane owns row q=lq; k = kg*16+g*4+r)
        float s[16];
        float mt = -1e30f;
#pragma unroll
        for (int kg = 0; kg < 4; ++kg) {
#pragma unroll
            for (int r = 0; r < 4; ++r) {
                const int kidx = kg * 16 + g * 4 + r;
                float2 ac = akck[kidx];
                int ck = __float_as_int(ac.y);
                int ce = ck & ~(ck >> 31);  // max(ck,0)
                float btv = bthp[-ce];
                float sv = sa[kg][r];
                float gsel = (qb && ck >= 0) ? 1.f : 0.f;
                sv = fmaf(gsel * (aq + ac.x), btv, sv);
                sv = (kt0 + kidx < N_) ? sv : -1e30f;
                s[kg * 4 + r] = sv;
                mt = fmaxf(mt, sv);
            }
        }
        mt = fmaxf(mt, __shfl_xor(mt, 16));
        mt = fmaxf(mt, __shfl_xor(mt, 32));
        const float mnew = fmaxf(m, mt);
        const float cc = __expf(m - mnew);
        m = mnew;
        lsum *= cc;
        float cc4[4];
#pragma unroll
        for (int r = 0; r < 4; ++r) cc4[r] = __shfl(cc, g * 4 + r);
#pragma unroll
        for (int dg = 0; dg < 4; ++dg) {
#pragma unroll
            for (int r = 0; r < 4; ++r) o[dg][r] *= cc4[r];
        }
        float pv[16];
#pragma unroll
        for (int j = 0; j < 16; ++j) {
            pv[j] = __expf(s[j] - m);
            lsum += pv[j];
        }
#pragma unroll
        for (int kg = 0; kg < 4; ++kg) {
            half4v ph;
            ph[0] = (_Float16)pv[kg * 4 + 0]; ph[1] = (_Float16)pv[kg * 4 + 1];
            ph[2] = (_Float16)pv[kg * 4 + 2]; ph[3] = (_Float16)pv[kg * 4 + 3];
            *(half4v*)&Pl[w][lq * 72 + kg * 16 + g * 4] = ph;
        }

        // ---- PV: C[q][d] += P[q][k] V[k][d]; A = P (from Pl), B = V (from Vt)
#pragma unroll
        for (int kh = 0; kh < 2; ++kh) {
            half8 pa = *(half8*)&Pl[w][lq * 72 + kh * 32 + g * 8];
#pragma unroll
            for (int dg = 0; dg < 4; ++dg) {
                const int d = dg * 16 + lq;
                half8 vb = *(half8*)&Vt[d * 64 + ((kh * 32 + g * 8) ^ ((d & 7) << 3))];
                o[dg] = __builtin_amdgcn_mfma_f32_16x16x32_f16(pa, vb, o[dg], 0, 0, 0);
            }
        }
    }

    lsum += __shfl_xor(lsum, 16);
    lsum += __shfl_xor(lsum, 32);
    const float linv = 1.f / lsum;
    float li4[4];
#pragma unroll
    for (int r = 0; r < 4; ++r) li4[r] = __shfl(linv, g * 4 + r);
#pragma unroll
    for (int dg = 0; dg < 4; ++dg) {
#pragma unroll
        for (int r = 0; r < 4; ++r) {
            const int qq = qt * 64 + w * 16 + g * 4 + r;
            if (qq < N_) OUT[base + (size_t)qq * D_ + dg * 16 + lq] = o[dg][r] * li4[r];
        }
    }
}

extern "C" void kernel_launch(void* const* d_in, const int* in_sizes, int n_in,
                              void* d_out, int out_size, void* d_ws, size_t ws_size,
                              hipStream_t stream) {
    const float* q = (const float*)d_in[0];
    const float* k = (const float*)d_in[1];
    const float* v = (const float*)d_in[2];
    const float* mu = (const float*)d_in[3];
    const float* w1 = (const float*)d_in[4];
    const float* b1 = (const float*)d_in[5];
    const float* w2 = (const float*)d_in[6];
    const float* gamma = (const float*)d_in[7];
    const float* rel = (const float*)d_in[8];
    // d_in[9] = idx_table: reconstructed analytically, never read.

    float* btT = (float*)d_ws;  // H_ * TBL_ floats = 190 KB

    cpb_mlp<<<(TBL_ + 255) / 256, 256, 0, stream>>>(rel, w1, b1, w2, btT);
    flex_attn<<<NBLK, 256, 0, stream>>>(q, k, v, mu, gamma, btT, (float*)d_out);
}

// Round 3
// 79.300 us; speedup vs baseline: 8.1247x; 1.3099x over previous
//
#include <hip/hip_runtime.h>
#include <math.h>

#define B_ 4
#define H_ 12
#define N_ 1025
#define D_ 64
#define HID_ 32
#define TBL_ 3969            // (2*32-1)^2
#define NQT 17               // ceil(1025/64) k-tiles and q-tiles
#define NBLK (B_ * H_ * NQT) // 816, divisible by 8
#define NFRAG (B_ * H_ * NQT * 8 * 64)  // 417792 fragment-threads
#define PSTR 76              // Pl row stride in f16 (152B: 8B-aligned, ~2-way banks)
#define LOG2E 1.44269504f

typedef _Float16 half8 __attribute__((ext_vector_type(8)));
typedef _Float16 half4v __attribute__((ext_vector_type(4)));
typedef float f32x4 __attribute__((ext_vector_type(4)));

#if defined(__has_builtin)
#if __has_builtin(__builtin_amdgcn_exp2f)
#define EX2 __builtin_amdgcn_exp2f
#else
#define EX2 exp2f
#endif
#else
#define EX2 exp2f
#endif

__device__ __forceinline__ void stage16(const _Float16* gsrc, _Float16* ldst) {
    __builtin_amdgcn_global_load_lds(
        (const __attribute__((address_space(1))) void*)gsrc,
        (__attribute__((address_space(3))) void*)ldst, 16, 0, 0);
}

// ---------------- prep: K/V -> f16 fragment-order tiles, akT, bias-table MLP
// Kf/Vf layout (f16): [((bh*17 + kt)*8 + fb)*512 + lane*8 + j]
//   K frag fb = kg*2+dh: value = K[bh][kt*64 + kg*16 + (lane&15)][dh*32 + (lane>>4)*8 + j]
//   V frag fb = kh*4+dg: value = V[bh][kt*64 + kh*32 + (lane>>4)*8 + j][dg*16 + (lane&15)]
// akT[bh*1088 + k] = sigmoid(gamma)*log2e*mu_k (0 if k invalid)
__global__ void prep(const float* __restrict__ K, const float* __restrict__ V,
                     const float* __restrict__ MU, const float* __restrict__ GAMMA,
                     const float* __restrict__ rel, const float* __restrict__ w1,
                     const float* __restrict__ b1, const float* __restrict__ w2,
                     _Float16* __restrict__ Kf, _Float16* __restrict__ Vf,
                     float* __restrict__ akT, float* __restrict__ btT) {
    const int gt = blockIdx.x * 256 + threadIdx.x;
    if (gt < NFRAG) {
        const int lane = gt & 63;
        const int fb = (gt >> 6) & 7;
        const int kt = (gt >> 9) % NQT;
        const int bh = gt / (NQT * 512);
        const int lq = lane & 15, g = lane >> 4;
        const size_t base = (size_t)bh * (N_ * D_);
        const size_t ob = ((size_t)(bh * NQT + kt) * 8 + fb) * 512 + lane * 8;
        {   // K fragment
            const int row = kt * 64 + (fb >> 1) * 16 + lq;
            const int col = (fb & 1) * 32 + g * 8;
            half8 k8;
            if (row < N_) {
                const float4* p = (const float4*)(K + base + (size_t)row * D_ + col);
                float4 a = p[0], b = p[1];
                k8[0] = (_Float16)a.x; k8[1] = (_Float16)a.y;
                k8[2] = (_Float16)a.z; k8[3] = (_Float16)a.w;
                k8[4] = (_Float16)b.x; k8[5] = (_Float16)b.y;
                k8[6] = (_Float16)b.z; k8[7] = (_Float16)b.w;
            } else {
#pragma unroll
                for (int j = 0; j < 8; ++j) k8[j] = (_Float16)0.f;
            }
            *(half8*)&Kf[ob] = k8;
        }
        {   // V fragment (transposed gather)
            const int kh = fb >> 2, dg = fb & 3;
            const int col = dg * 16 + lq;
            const int r0 = kt * 64 + kh * 32 + g * 8;
            half8 v8;
#pragma unroll
            for (int j = 0; j < 8; ++j) {
                const int row = r0 + j;
                v8[j] = (row < N_) ? (_Float16)V[base + (size_t)row * D_ + col] : (_Float16)0.f;
            }
            *(half8*)&Vf[ob] = v8;
        }
    }
    if (gt < B_ * H_ * 1088) {
        const int bh = gt / 1088;
        const int k = gt - bh * 1088;
        const int h = bh % H_;
        const float sgl = LOG2E / (1.f + __expf(-GAMMA[h]));
        float a = 0.f;
        if (k >= 1 && k < N_) a = sgl * MU[((size_t)bh * 2 + 1) * N_ + k];
        akT[gt] = a;
    }
    const int i = gt - NFRAG;
    if (i >= 0 && i < TBL_) {
        float x0 = rel[2 * i + 0], x1 = rel[2 * i + 1];
        float acc[H_];
#pragma unroll
        for (int h = 0; h < H_; ++h) acc[h] = 0.f;
#pragma unroll
        for (int j = 0; j < HID_; ++j) {
            float t = fmaf(x0, w1[j], fmaf(x1, w1[HID_ + j], b1[j]));
            float gl = 0.5f * t * (1.f + erff(t * 0.7071067811865475f));  // exact gelu
#pragma unroll
            for (int h = 0; h < H_; ++h) acc[h] = fmaf(gl, w2[j * H_ + h], acc[h]);
        }
#pragma unroll
        for (int h = 0; h < H_; ++h) btT[h * TBL_ + i] = acc[h];
    }
}

// ---------------- fused flash attention, f16 MFMA, DMA-staged fragment tiles
__global__ __launch_bounds__(256, 3) void flex_attn(
    const float* __restrict__ Q, const _Float16* __restrict__ Kf,
    const _Float16* __restrict__ Vf, const float* __restrict__ MU,
    const float* __restrict__ GAMMA, const float* __restrict__ btT,
    const float* __restrict__ akT, float* __restrict__ OUT) {
    __shared__ __align__(16) _Float16 Ks[2][4096];
    __shared__ __align__(16) _Float16 Vs[2][4096];
    __shared__ __align__(16) _Float16 Pl[4][16 * PSTR];

    const int bid = blockIdx.x;
    const int swz = (bid & 7) * (NBLK / 8) + (bid >> 3);  // bijective: 816 % 8 == 0
    const int bh = swz / NQT;
    const int qt = swz % NQT;
    const int h = bh % H_;
    const int tid = threadIdx.x;
    const int w = tid >> 6;
    const int lane = tid & 63;
    const int lq = lane & 15;
    const int g = lane >> 4;

    const size_t base = (size_t)bh * (N_ * D_);
    const float sg = LOG2E / (1.f + __expf(-GAMMA[h]));

    const int qrow = qt * 64 + w * 16 + lq;
    const bool qv = qrow < N_;

    // Q fragment (B-operand of swapped QK^T), scale = 1/sqrt(64) * log2(e)
    half8 qf[2];
#pragma unroll
    for (int dh = 0; dh < 2; ++dh) {
        float4 t0 = make_float4(0, 0, 0, 0), t1 = t0;
        if (qv) {
            const float4* qp = (const float4*)(Q + base + (size_t)qrow * D_ + dh * 32 + g * 8);
            t0 = qp[0]; t1 = qp[1];
        }
        const float qs = 0.125f * LOG2E;
        half8 q8;
        q8[0] = (_Float16)(t0.x * qs); q8[1] = (_Float16)(t0.y * qs);
        q8[2] = (_Float16)(t0.z * qs); q8[3] = (_Float16)(t0.w * qs);
        q8[4] = (_Float16)(t1.x * qs); q8[5] = (_Float16)(t1.y * qs);
        q8[6] = (_Float16)(t1.z * qs); q8[7] = (_Float16)(t1.w * qs);
        qf[dh] = q8;
    }

    const bool qb = qv && (qrow >= 1);
    float aq = 0.f;
    int cq = 0;
    if (qb) {
        int pq = qrow - 1;
        cq = (pq >> 5) * 63 + (pq & 31);
        aq = sg * MU[(size_t)bh * 2 * N_ + qrow];  // sg*log2e*mu_q
    }
    const float* bthp = btT + h * TBL_ + cq + 1984;  // bias = bthp[-ck]
    const float* akb = akT + bh * 1088;
    const _Float16* kfb = Kf + (size_t)bh * NQT * 4096;
    const _Float16* vfb = Vf + (size_t)bh * NQT * 4096;

    f32x4 o[4];
    const f32x4 zz = {0.f, 0.f, 0.f, 0.f};
#pragma unroll
    for (int dg = 0; dg < 4; ++dg) o[dg] = zz;
    float m = -1e30f, lsum = 0.f;

    // prologue: stage tile 0 into buf 0 (each wave: 2 K-chunks + 2 V-chunks of 1KB)
    stage16(kfb + (2 * w + 0) * 512 + lane * 8, &Ks[0][(2 * w + 0) * 512]);
    stage16(kfb + (2 * w + 1) * 512 + lane * 8, &Ks[0][(2 * w + 1) * 512]);
    stage16(vfb + (2 * w + 0) * 512 + lane * 8, &Vs[0][(2 * w + 0) * 512]);
    stage16(vfb + (2 * w + 1) * 512 + lane * 8, &Vs[0][(2 * w + 1) * 512]);
    __syncthreads();

    for (int t = 0; t < NQT; ++t) {
        const int buf = t & 1;
        const int kt0 = t * 64;

        // ---- bias operand loads (L1-resident; independent of staging)
        float bt16[16], sel16[16];
#pragma unroll
        for (int kg = 0; kg < 4; ++kg) {
#pragma unroll
            for (int r = 0; r < 4; ++r) {
                const int i = kg * 4 + r;
                const int kidx = kt0 + kg * 16 + g * 4 + r;
                const int pk = kidx - 1;
                const bool vb = (unsigned)pk < 1024u;  // bias-valid k
                const int ck = (pk >> 5) * 63 + (pk & 31);
                bt16[i] = bthp[-(vb ? ck : 0)];
                const float akv = akb[kidx];
                sel16[i] = (vb && qb) ? (aq + akv) : 0.f;
            }
        }

        // ---- stage next tile into the other buffer (completes by the barrier)
        if (t + 1 < NQT) {
            const _Float16* kn = kfb + (size_t)(t + 1) * 4096;
            const _Float16* vn = vfb + (size_t)(t + 1) * 4096;
            stage16(kn + (2 * w + 0) * 512 + lane * 8, &Ks[buf ^ 1][(2 * w + 0) * 512]);
            stage16(kn + (2 * w + 1) * 512 + lane * 8, &Ks[buf ^ 1][(2 * w + 1) * 512]);
            stage16(vn + (2 * w + 0) * 512 + lane * 8, &Vs[buf ^ 1][(2 * w + 0) * 512]);
            stage16(vn + (2 * w + 1) * 512 + lane * 8, &Vs[buf ^ 1][(2 * w + 1) * 512]);
        }

        // ---- QK^T (swapped): C[k][q]; A-frags contiguous-by-lane (conflict-free)
        const _Float16* ksl = &Ks[buf][lane * 8];
        f32x4 sa[4];
#pragma unroll
        for (int kg = 0; kg < 4; ++kg) {
            half8 a0 = *(const half8*)(ksl + (2 * kg + 0) * 512);
            half8 a1 = *(const half8*)(ksl + (2 * kg + 1) * 512);
            f32x4 z = zz;
            z = __builtin_amdgcn_mfma_f32_16x16x32_f16(a0, qf[0], z, 0, 0, 0);
            z = __builtin_amdgcn_mfma_f32_16x16x32_f16(a1, qf[1], z, 0, 0, 0);
            sa[kg] = z;
        }

        // ---- scores + online softmax (log2 domain)
        float s[16];
        float mt = -1e30f;
#pragma unroll
        for (int kg = 0; kg < 4; ++kg) {
#pragma unroll
            for (int r = 0; r < 4; ++r) {
                const int i = kg * 4 + r;
                float sv = fmaf(sel16[i], bt16[i], sa[kg][r]);
                if (t == NQT - 1) {  // only the last tile has k >= N
                    const int kidx = kt0 + kg * 16 + g * 4 + r;
                    sv = (kidx < N_) ? sv : -1e30f;
                }
                s[i] = sv;
                mt = fmaxf(mt, sv);
            }
        }
        mt = fmaxf(mt, __shfl_xor(mt, 16));
        mt = fmaxf(mt, __shfl_xor(mt, 32));
        const float mnew = fmaxf(m, mt);
        const float cc = EX2(m - mnew);
        m = mnew;
        lsum *= cc;
        float cc4[4];
#pragma unroll
        for (int r = 0; r < 4; ++r) cc4[r] = __shfl(cc, g * 4 + r);
#pragma unroll
        for (int dg = 0; dg < 4; ++dg) {
#pragma unroll
            for (int r = 0; r < 4; ++r) o[dg][r] *= cc4[r];
        }
        float pv[16];
#pragma unroll
        for (int i = 0; i < 16; ++i) {
            pv[i] = EX2(s[i] - m);
            lsum += pv[i];
        }
#pragma unroll
        for (int kg = 0; kg < 4; ++kg) {
            half4v ph;
            ph[0] = (_Float16)pv[kg * 4 + 0]; ph[1] = (_Float16)pv[kg * 4 + 1];
            ph[2] = (_Float16)pv[kg * 4 + 2]; ph[3] = (_Float16)pv[kg * 4 + 3];
            *(half4v*)&Pl[w][lq * PSTR + kg * 16 + g * 4] = ph;
        }

        // ---- PV: C[q][d] += P[q][k] V[k][d]
#pragma unroll
        for (int kh = 0; kh < 2; ++kh) {
            half4v plo = *(const half4v*)&Pl[w][lq * PSTR + kh * 32 + g * 8];
            half4v phi = *(const half4v*)&Pl[w][lq * PSTR + kh * 32 + g * 8 + 4];
            half8 pa;
            pa[0] = plo[0]; pa[1] = plo[1]; pa[2] = plo[2]; pa[3] = plo[3];
            pa[4] = phi[0]; pa[5] = phi[1]; pa[6] = phi[2]; pa[7] = phi[3];
#pragma unroll
            for (int dg = 0; dg < 4; ++dg) {
                half8 vb8 = *(const half8*)&Vs[buf][(kh * 4 + dg) * 512 + lane * 8];
                o[dg] = __builtin_amdgcn_mfma_f32_16x16x32_f16(pa, vb8, o[dg], 0, 0, 0);
            }
        }
        __syncthreads();
    }

    lsum += __shfl_xor(lsum, 16);
    lsum += __shfl_xor(lsum, 32);
    const float linv = 1.f / lsum;
    float li4[4];
#pragma unroll
    for (int r = 0; r < 4; ++r) li4[r] = __shfl(linv, g * 4 + r);
#pragma unroll
    for (int dg = 0; dg < 4; ++dg) {
#pragma unroll
        for (int r = 0; r < 4; ++r) {
            const int qq = qt * 64 + w * 16 + g * 4 + r;
            if (qq < N_) OUT[base + (size_t)qq * D_ + dg * 16 + lq] = o[dg][r] * li4[r];
        }
    }
}

extern "C" void kernel_launch(void* const* d_in, const int* in_sizes, int n_in,
                              void* d_out, int out_size, void* d_ws, size_t ws_size,
                              hipStream_t stream) {
    const float* q = (const float*)d_in[0];
    const float* k = (const float*)d_in[1];
    const float* v = (const float*)d_in[2];
    const float* mu = (const float*)d_in[3];
    const float* w1 = (const float*)d_in[4];
    const float* b1 = (const float*)d_in[5];
    const float* w2 = (const float*)d_in[6];
    const float* gamma = (const float*)d_in[7];
    const float* rel = (const float*)d_in[8];
    // d_in[9] = idx_table: reconstructed analytically, never read.

    // ws layout (bytes):
    //   btT  @ 0         : 12*3969*4      = 190512
    //   Kf   @ 190512    : 48*17*4096*2   = 6684672
    //   Vf   @ 6875184   : 6684672
    //   akT  @ 13559856  : 48*1088*4      = 208896   (total 13768752)
    char* ws = (char*)d_ws;
    float* btT = (float*)(ws + 0);
    _Float16* Kf = (_Float16*)(ws + 190512);
    _Float16* Vf = (_Float16*)(ws + 6875184);
    float* akT = (float*)(ws + 13559856);

    const int prep_blocks = (NFRAG + TBL_ + 255) / 256;  // 1648
    prep<<<prep_blocks, 256, 0, stream>>>(k, v, mu, gamma, rel, w1, b1, w2, Kf, Vf, akT, btT);
    flex_attn<<<NBLK, 256, 0, stream>>>(q, Kf, Vf, mu, gamma, btT, akT, (float*)d_out);
}

// Round 5
// 65.586 us; speedup vs baseline: 9.8237x; 1.2091x over previous
//
#include <hip/hip_runtime.h>
#include <math.h>

#define B_ 4
#define H_ 12
#define N_ 1025
#define D_ 64
#define HID_ 32
#define TBL_ 3969            // (2*32-1)^2
#define NQT 17               // 64-row tiles in both q and k
#define NBLK (B_ * H_ * NQT) // 816, divisible by 8
#define LOG2E 1.44269504f
#define THR_ 12.0f           // defer-max threshold (log2 domain); p <= 2^12 fits f16

typedef _Float16 half8 __attribute__((ext_vector_type(8)));
typedef __fp16 fp16x2 __attribute__((ext_vector_type(2)));
typedef float f32x4 __attribute__((ext_vector_type(4)));

#if defined(__has_builtin)
#if __has_builtin(__builtin_amdgcn_exp2f)
#define EX2 __builtin_amdgcn_exp2f
#else
#define EX2 exp2f
#endif
#else
#define EX2 exp2f
#endif

// ws layout (bytes):
//   btT @ 0        : 12*3969*4 = 190512
//   akT @ 190512   : 48*1088*4 = 208896   (also the finite overrun pad for btT)
//   Kf  @ 399408   : 48*17*4096*2 = 6684672
//   Vf  @ 7084080  : 6684672              (end 13768752)
#define BTT_OFF 0
#define AKT_OFF 190512
#define KF_OFF 399408
#define VF_OFF 7084080

__device__ __forceinline__ void stage16(const _Float16* gsrc, _Float16* ldst) {
    __builtin_amdgcn_global_load_lds(
        (const __attribute__((address_space(1))) void*)gsrc,
        (__attribute__((address_space(3))) void*)ldst, 16, 0, 0);
}

// ---------------- prep: K/V -> f16 fragment-order tiles (V via LDS transpose),
// akT = sigmoid(gamma)*log2e*mu_k, btT = MLP bias table (per-head transposed)
__global__ __launch_bounds__(256) void prep(
    const float* __restrict__ K, const float* __restrict__ V,
    const float* __restrict__ MU, const float* __restrict__ GAMMA,
    const float* __restrict__ rel, const float* __restrict__ w1,
    const float* __restrict__ b1, const float* __restrict__ w2,
    _Float16* __restrict__ Kf, _Float16* __restrict__ Vf,
    float* __restrict__ akT, float* __restrict__ btT) {
    const int bid = blockIdx.x;
    const int tid = threadIdx.x;
    if (bid < NBLK) {
        __shared__ float Vls[64 * 65];  // [d][k], pad 65 (2-way banks max)
        const int bh = bid / NQT, kt = bid % NQT;
        const size_t base = (size_t)bh * (N_ * D_);
        const int k0 = kt * 64;
        // V rows: coalesced global read -> transposed LDS scatter
#pragma unroll
        for (int it = 0; it < 4; ++it) {
            const int idx = it * 256 + tid;
            const int kr = idx >> 4, c4 = (idx & 15) << 2;
            const int kg = k0 + kr;
            float4 v4 = make_float4(0, 0, 0, 0);
            if (kg < N_) v4 = *(const float4*)(V + base + (size_t)kg * D_ + c4);
            Vls[(c4 + 0) * 65 + kr] = v4.x;
            Vls[(c4 + 1) * 65 + kr] = v4.y;
            Vls[(c4 + 2) * 65 + kr] = v4.z;
            Vls[(c4 + 3) * 65 + kr] = v4.w;
        }
        __syncthreads();
        const int lane = tid & 63, lq = lane & 15, g = lane >> 4;
        const int fbh = tid >> 6;
        const size_t tb = (size_t)(bh * NQT + kt) * 4096;
#pragma unroll
        for (int x = 0; x < 2; ++x) {
            const int fb = fbh + x * 4;
            {   // V fragment fb = kh*4+dg from LDS
                const int kh = fb >> 2, dg = fb & 3;
                const float* vp = &Vls[(dg * 16 + lq) * 65 + kh * 32 + g * 8];
                half8 v8;
#pragma unroll
                for (int j = 0; j < 8; ++j) v8[j] = (_Float16)vp[j];
                *(half8*)&Vf[tb + fb * 512 + lane * 8] = v8;
            }
            {   // K fragment fb = kg2*2+dh, direct
                const int row = k0 + (fb >> 1) * 16 + lq;
                const int col = (fb & 1) * 32 + g * 8;
                half8 k8;
                if (row < N_) {
                    const float4* p = (const float4*)(K + base + (size_t)row * D_ + col);
                    float4 a = p[0], b = p[1];
                    k8[0] = (_Float16)a.x; k8[1] = (_Float16)a.y;
                    k8[2] = (_Float16)a.z; k8[3] = (_Float16)a.w;
                    k8[4] = (_Float16)b.x; k8[5] = (_Float16)b.y;
                    k8[6] = (_Float16)b.z; k8[7] = (_Float16)b.w;
                } else {
#pragma unroll
                    for (int j = 0; j < 8; ++j) k8[j] = (_Float16)0.f;
                }
                *(half8*)&Kf[tb + fb * 512 + lane * 8] = k8;
            }
        }
        if (tid < 64) {
            const int kk = k0 + tid;
            const int h = bh % H_;
            const float sgl = LOG2E / (1.f + __expf(-GAMMA[h]));
            float a = 0.f;
            if (kk >= 1 && kk < N_) a = sgl * MU[((size_t)bh * 2 + 1) * N_ + kk];
            akT[bh * 1088 + kk] = a;
        }
    } else {
        const int i = (bid - NBLK) * 256 + tid;
        if (i < TBL_) {
            const float x0 = rel[2 * i + 0], x1 = rel[2 * i + 1];
            float acc[H_];
#pragma unroll
            for (int h = 0; h < H_; ++h) acc[h] = 0.f;
#pragma unroll
            for (int j = 0; j < HID_; ++j) {
                float t = fmaf(x0, w1[j], fmaf(x1, w1[HID_ + j], b1[j]));
                float gl = 0.5f * t * (1.f + erff(t * 0.7071067811865475f));  // exact gelu
#pragma unroll
                for (int h = 0; h < H_; ++h) acc[h] = fmaf(gl, w2[j * H_ + h], acc[h]);
            }
#pragma unroll
            for (int h = 0; h < H_; ++h) btT[h * TBL_ + i] = acc[h];
        }
    }
}

// ---------------- fused flash attention, f16 MFMA, DMA-staged fragment tiles
__global__ __launch_bounds__(256, 4) void flex_attn(
    const float* __restrict__ Q, const _Float16* __restrict__ Kf,
    const _Float16* __restrict__ Vf, const float* __restrict__ MU,
    const float* __restrict__ GAMMA, const char* __restrict__ btb,  // ws - 2048
    const float* __restrict__ akT, float* __restrict__ OUT) {
    __shared__ __align__(16) _Float16 Ks[2][4096];
    __shared__ __align__(16) _Float16 Vs[2][4096];
    __shared__ __align__(16) _Float16 Pl[4][1024];  // [wave][16 q][64 k] XOR-swizzled

    const int bid = blockIdx.x;
    const int swz0 = (bid & 7) * (NBLK / 8) + (bid >> 3);  // bijective XCD swizzle
    const int bh = swz0 / NQT;
    const int qt = swz0 % NQT;
    const int h = bh % H_;
    const int tid = threadIdx.x;
    const int w = tid >> 6;
    const int lane = tid & 63;
    const int lq = lane & 15;
    const int g = lane >> 4;

    const size_t base = (size_t)bh * (N_ * D_);
    const float sg = LOG2E / (1.f + __expf(-GAMMA[h]));

    const int qrow = qt * 64 + w * 16 + lq;
    const bool qv = qrow < N_;

    // Q fragment (B-operand of swapped QK^T), scale = log2e/sqrt(64)
    half8 qf[2];
#pragma unroll
    for (int dh = 0; dh < 2; ++dh) {
        float4 t0 = make_float4(0, 0, 0, 0), t1 = t0;
        if (qv) {
            const float4* qp = (const float4*)(Q + base + (size_t)qrow * D_ + dh * 32 + g * 8);
            t0 = qp[0]; t1 = qp[1];
        }
        const float qs = 0.125f * LOG2E;
        half8 q8;
        q8[0] = (_Float16)(t0.x * qs); q8[1] = (_Float16)(t0.y * qs);
        q8[2] = (_Float16)(t0.z * qs); q8[3] = (_Float16)(t0.w * qs);
        q8[4] = (_Float16)(t1.x * qs); q8[5] = (_Float16)(t1.y * qs);
        q8[6] = (_Float16)(t1.z * qs); q8[7] = (_Float16)(t1.w * qs);
        qf[dh] = q8;
    }

    const bool qb = qv && (qrow >= 1);
    const float qbf = qb ? 1.f : 0.f;
    float aq = 0.f;
    int cq = 0;
    if (qb) {
        const int pq = qrow - 1;
        cq = (pq >> 5) * 63 + (pq & 31);
        aq = sg * MU[(size_t)bh * 2 * N_ + qrow];  // sg*log2e*mu_q
    }
    // bias gather byte offsets vs btb = ws-2048: off = (h*TBL + cq + 1984 - ck)*4 + 2048
    // per-tile recurrence: ck += 126 exactly  =>  off -= 504
    int boffs[16];
#pragma unroll
    for (int kg = 0; kg < 4; ++kg) {
#pragma unroll
        for (int r = 0; r < 4; ++r) {
            const int pk = kg * 16 + g * 4 + r - 1;       // tile 0
            const int ck = (pk >> 5) * 63 + (pk & 31);    // arith shift: ck(-1) = -32
            boffs[kg * 4 + r] = (h * TBL_ + cq + 1984 - ck) * 4 + 2048;
        }
    }
    const float* akb = akT + bh * 1088;
    const _Float16* kfb = Kf + (size_t)bh * NQT * 4096;
    const _Float16* vfb = Vf + (size_t)bh * NQT * 4096;

    f32x4 o[4];
    const f32x4 zz = {0.f, 0.f, 0.f, 0.f};
#pragma unroll
    for (int dg = 0; dg < 4; ++dg) o[dg] = zz;
    float m = 0.f, lsum = 0.f;

    // prologue: stage tile 0 into buf 0
    stage16(kfb + (2 * w + 0) * 512 + lane * 8, &Ks[0][(2 * w + 0) * 512]);
    stage16(kfb + (2 * w + 1) * 512 + lane * 8, &Ks[0][(2 * w + 1) * 512]);
    stage16(vfb + (2 * w + 0) * 512 + lane * 8, &Vs[0][(2 * w + 0) * 512]);
    stage16(vfb + (2 * w + 1) * 512 + lane * 8, &Vs[0][(2 * w + 1) * 512]);
    __syncthreads();

    const int pswz = (lq & 7) << 4;
    char* plw = (char*)&Pl[w][0];

    for (int t = 0; t < NQT; ++t) {
        const int buf = t & 1;
        const int kt0 = t * 64;

        // ---- bias gathers (bare saddr loads; clamp floor is a no-op except masked corner)
        float bt16[16];
#pragma unroll
        for (int i = 0; i < 16; ++i) {
            int off = boffs[i];
            off = off < 2048 ? 2048 : off;
            bt16[i] = *(const float*)(btb + (uint32_t)off);
            boffs[i] -= 504;
        }
        // ---- gate k-terms (vectorized, r-consecutive)
        f32x4 akq[4];
#pragma unroll
        for (int kg = 0; kg < 4; ++kg)
            akq[kg] = *(const f32x4*)(akb + kt0 + kg * 16 + g * 4);

        // ---- stage next tile into the other buffer
        if (t + 1 < NQT) {
            const _Float16* kn = kfb + (size_t)(t + 1) * 4096;
            const _Float16* vn = vfb + (size_t)(t + 1) * 4096;
            stage16(kn + (2 * w + 0) * 512 + lane * 8, &Ks[buf ^ 1][(2 * w + 0) * 512]);
            stage16(kn + (2 * w + 1) * 512 + lane * 8, &Ks[buf ^ 1][(2 * w + 1) * 512]);
            stage16(vn + (2 * w + 0) * 512 + lane * 8, &Vs[buf ^ 1][(2 * w + 0) * 512]);
            stage16(vn + (2 * w + 1) * 512 + lane * 8, &Vs[buf ^ 1][(2 * w + 1) * 512]);
        }

        // ---- QK^T (swapped): C[k][q]; A-frags contiguous-by-lane (conflict-free)
        const _Float16* ksl = &Ks[buf][lane * 8];
        f32x4 sa[4];
#pragma unroll
        for (int kg = 0; kg < 4; ++kg) {
            half8 a0 = *(const half8*)(ksl + (2 * kg + 0) * 512);
            half8 a1 = *(const half8*)(ksl + (2 * kg + 1) * 512);
            f32x4 z = zz;
            z = __builtin_amdgcn_mfma_f32_16x16x32_f16(a0, qf[0], z, 0, 0, 0);
            z = __builtin_amdgcn_mfma_f32_16x16x32_f16(a1, qf[1], z, 0, 0, 0);
            sa[kg] = z;
        }

        // ---- scores (log2 domain): s = sa + (qbf*ak + aq)*bt
        if (t == 0 && g == 0) bt16[0] = 0.f;  // k=0 column has no bias
        float s[16];
#pragma unroll
        for (int kg = 0; kg < 4; ++kg) {
#pragma unroll
            for (int r = 0; r < 4; ++r) {
                const int i = kg * 4 + r;
                s[i] = fmaf(fmaf(qbf, akq[kg][r], aq), bt16[i], sa[kg][r]);
            }
        }
        if (t == NQT - 1) {  // mask k >= N (only k=1024 = i0,g0 survives)
#pragma unroll
            for (int kg = 0; kg < 4; ++kg)
#pragma unroll
                for (int r = 0; r < 4; ++r) {
                    const int i = kg * 4 + r;
                    if (1024 + kg * 16 + g * 4 + r >= N_) s[i] = -1e30f;
                }
        }

        // ---- defer-max online softmax: no cross-lane work in the common path
        float lmax = s[0];
#pragma unroll
        for (int i = 1; i < 16; ++i) lmax = fmaxf(lmax, s[i]);
        if (t == 0) {
            float mt = fmaxf(lmax, __shfl_xor(lmax, 16));
            m = fmaxf(mt, __shfl_xor(mt, 32));
        } else if (!__all(lmax <= m + THR_)) {
            float mt = fmaxf(lmax, __shfl_xor(lmax, 16));
            mt = fmaxf(mt, __shfl_xor(mt, 32));
            const float mnew = fmaxf(m, mt);
            const float cc = EX2(m - mnew);
            m = mnew;
            lsum *= cc;
            float cc4[4];
#pragma unroll
            for (int r = 0; r < 4; ++r) cc4[r] = __shfl(cc, g * 4 + r);
#pragma unroll
            for (int dg = 0; dg < 4; ++dg)
#pragma unroll
                for (int r = 0; r < 4; ++r) o[dg][r] *= cc4[r];
        }
        float pv16[16];
        float ls0 = 0.f, ls1 = 0.f;
#pragma unroll
        for (int i = 0; i < 16; i += 2) {
            pv16[i] = EX2(s[i] - m);
            pv16[i + 1] = EX2(s[i + 1] - m);
            ls0 += pv16[i];
            ls1 += pv16[i + 1];
        }
        lsum += ls0 + ls1;

        // ---- P -> f16, XOR-swizzled per-wave LDS
#pragma unroll
        for (int kg = 0; kg < 4; ++kg) {
            fp16x2 h0 = __builtin_amdgcn_cvt_pkrtz(pv16[kg * 4 + 0], pv16[kg * 4 + 1]);
            fp16x2 h1 = __builtin_amdgcn_cvt_pkrtz(pv16[kg * 4 + 2], pv16[kg * 4 + 3]);
            uint2 u = make_uint2(__builtin_bit_cast(uint32_t, h0),
                                 __builtin_bit_cast(uint32_t, h1));
            *(uint2*)(plw + lq * 128 + ((kg * 32 + g * 8) ^ pswz)) = u;
        }

        // ---- PV: C[q][d] += P[q][k] V[k][d]
#pragma unroll
        for (int kh = 0; kh < 2; ++kh) {
            half8 pa = *(const half8*)(plw + lq * 128 + ((kh * 64 + g * 16) ^ pswz));
#pragma unroll
            for (int dg = 0; dg < 4; ++dg) {
                half8 vb8 = *(const half8*)&Vs[buf][(kh * 4 + dg) * 512 + lane * 8];
                o[dg] = __builtin_amdgcn_mfma_f32_16x16x32_f16(pa, vb8, o[dg], 0, 0, 0);
            }
        }
        __syncthreads();
    }

    lsum += __shfl_xor(lsum, 16);
    lsum += __shfl_xor(lsum, 32);
    const float linv = 1.f / lsum;
    float li4[4];
#pragma unroll
    for (int r = 0; r < 4; ++r) li4[r] = __shfl(linv, g * 4 + r);
#pragma unroll
    for (int dg = 0; dg < 4; ++dg) {
#pragma unroll
        for (int r = 0; r < 4; ++r) {
            const int qq = qt * 64 + w * 16 + g * 4 + r;
            if (qq < N_) OUT[base + (size_t)qq * D_ + dg * 16 + lq] = o[dg][r] * li4[r];
        }
    }
}

extern "C" void kernel_launch(void* const* d_in, const int* in_sizes, int n_in,
                              void* d_out, int out_size, void* d_ws, size_t ws_size,
                              hipStream_t stream) {
    const float* q = (const float*)d_in[0];
    const float* k = (const float*)d_in[1];
    const float* v = (const float*)d_in[2];
    const float* mu = (const float*)d_in[3];
    const float* w1 = (const float*)d_in[4];
    const float* b1 = (const float*)d_in[5];
    const float* w2 = (const float*)d_in[6];
    const float* gamma = (const float*)d_in[7];
    const float* rel = (const float*)d_in[8];
    // d_in[9] = idx_table: reconstructed analytically, never read.

    char* ws = (char*)d_ws;
    float* btT = (float*)(ws + BTT_OFF);
    float* akT = (float*)(ws + AKT_OFF);
    _Float16* Kf = (_Float16*)(ws + KF_OFF);
    _Float16* Vf = (_Float16*)(ws + VF_OFF);

    prep<<<NBLK + (TBL_ + 255) / 256, 256, 0, stream>>>(k, v, mu, gamma, rel, w1, b1, w2,
                                                        Kf, Vf, akT, btT);
    flex_attn<<<NBLK, 256, 0, stream>>>(q, Kf, Vf, mu, gamma, ws - 2048, akT, (float*)d_out);
}